// Round 23
// baseline (400.758 us; speedup 1.0000x reference)
//
#include <hip/hip_runtime.h>
#include <hip/hip_fp16.h>

// DEQ classifier, WAVE-PER-IMAGE, ZERO-BARRIER main loop.
// 1024 blocks x 64 threads; each wave owns one image entirely. The 30-iter
// fixed-point loop contains NO __syncthreads / s_barrier at all:
//   - conv1 processed in 4 row-bands of 8 (acc[8]); GN stats accumulate in
//     registers across bands; stats reduce = pure __shfl wave-reduce
//   - h written UNNORMALIZED; conv2 absorbs GN via the R22-VERIFIED
//     indicator trick: h ch6 = f16 1.0 interior / 0 pads (set once);
//     fw dwords0-2 = w2*sc (hmul2), dword3 = pk2(padw,0),
//     padw = sum_ch w2[oc][ch][tap]*sh[ch]  -> exact normalized conv
//   - conv2 in 4 row-bands; z RMW per band
//   Same-wave LDS RAW ordering is hardware-enforced (lgkmcnt) -- no barriers.
// LDS (one 71-row x 36-bundle combined buffer, 8-ch f16 bundles, 16 B):
//   rows 0..35 zx plane (interior 2..33; z0..z4,img0..2), rows 34..69 h
//   plane (interior 36..67), rows 34/35 shared ZERO pad, row 70 guard
//   (absorbs row-reuse tx=6/7 overreads; R18 NaN lesson). 40896 B/block ->
//   up to 4 blocks/CU by LDS; 1 wave/SIMD, no cross-wave coupling.
// Conv MFMA 16x16x32 row-reuse (R15): chunk (ty,txh): A=weight frag, ONE
// B-read per pixel row feeds outputs g=pr-ty. One MFMA covers a FULL 32-px
// image row (cols = 16 anchors x 2 dx). D: col=lane&15, row=(lane>>4)*4+reg.
// Frag tables in VGPRs (f1,f2 raw, fw folded: 120 regs; launch_bounds(64,1)
// -> cap 256). Tripwire: FETCH_SIZE ~7 MB; spill shows as FETCH/WRITE blowup.
// WHY: R16-R22 showed the ~310us plateau is cross-wave barrier/dependency
// latency at pinned ~8 waves/CU; paying work for fewer barriers always lost.
// This removes the coupling instead of paying for it.

typedef _Float16 half8 __attribute__((ext_vector_type(8)));
typedef float f32x4 __attribute__((ext_vector_type(4)));

#define HOFF 34
#define NBUF (71 * 36 * 4)        // 10224 dwords = 40896 B

__device__ __forceinline__ unsigned pk2(float a, float b) {
    __half2 h = __float22half2_rn(make_float2(a, b));
    return *reinterpret_cast<unsigned*>(&h);
}
__device__ __forceinline__ float2 up2(unsigned u) {
    __half2 h = *reinterpret_cast<__half2*>(&u);
    return __half22float2(h);
}
__device__ __forceinline__ unsigned hmul2(unsigned a, unsigned b) {
    __half2 r = __hmul2(*reinterpret_cast<__half2*>(&a), *reinterpret_cast<__half2*>(&b));
    return *reinterpret_cast<unsigned*>(&r);
}
__device__ __forceinline__ float lrelu(float x) { return fmaxf(x, 0.01f * x); }
__device__ __forceinline__ int swz(int x) { return (x * 16) ^ ((x & 8) << 1); }
__device__ __forceinline__ int bofs(int r, int x) { return r * 576 + swz(x); }

// ---- prep: row-reuse A-fragments (R15/R22 layout) ----
// ws[0..2559]    : conv1 frags, chunk c=(ty*2+txh), lane l:
//   row=l&15 (dx=row>>3, oc=row&7), tg=l>>4, tx=4*txh+tg, kx=tx-dx
//   elem pair d = ch (2d,2d+1): w1[oc][ch][ty][kx], 0 if oc>=6 or kx OOB
// ws[2560..5119] : conv2 frags from w2 (0 if oc>=5, ch>=6)
__global__ void pack_weights(const float* __restrict__ w1,
                             const float* __restrict__ w2,
                             unsigned* __restrict__ ws)
{
    int t = blockIdx.x * 256 + threadIdx.x;
    if (t < 640) {
        int c = t >> 6, l = t & 63;
        int row = l & 15, tg = l >> 4;
        int dx = row >> 3, oc = row & 7;
        int ty = c >> 1, tx = 4 * (c & 1) + tg, kx = tx - dx;
        unsigned q[4];
        #pragma unroll
        for (int d = 0; d < 4; ++d) {
            float v0 = 0.f, v1 = 0.f;
            if (oc < 6 && kx >= 0 && kx < 5) {
                v0 = w1[(oc * 8 + 2 * d) * 25 + ty * 5 + kx];
                v1 = w1[(oc * 8 + 2 * d + 1) * 25 + ty * 5 + kx];
            }
            q[d] = pk2(v0, v1);
        }
        *(uint4*)&ws[t * 4] = make_uint4(q[0], q[1], q[2], q[3]);
    } else if (t < 1280) {
        int u = t - 640;
        int c = u >> 6, l = u & 63;
        int row = l & 15, tg = l >> 4;
        int dx = row >> 3, oc = row & 7;
        int ty = c >> 1, tx = 4 * (c & 1) + tg, kx = tx - dx;
        unsigned q[4];
        #pragma unroll
        for (int d = 0; d < 4; ++d) {
            float v0 = 0.f, v1 = 0.f;
            if (oc < 5 && kx >= 0 && kx < 5) {
                if (2 * d < 6)     v0 = w2[(oc * 6 + 2 * d) * 25 + ty * 5 + kx];
                if (2 * d + 1 < 6) v1 = w2[(oc * 6 + 2 * d + 1) * 25 + ty * 5 + kx];
            }
            q[d] = pk2(v0, v1);
        }
        *(uint4*)&ws[2560 + u * 4] = make_uint4(q[0], q[1], q[2], q[3]);
    }
}

__global__ __launch_bounds__(64, 1)
void deq_kernel(const float* __restrict__ image,
                const unsigned* __restrict__ wks,
                const float* __restrict__ b1,
                const float* __restrict__ gam, const float* __restrict__ bet,
                const float* __restrict__ b2,
                const float* __restrict__ wh, const float* __restrict__ bh,
                float* __restrict__ out)
{
    __shared__ __align__(16) unsigned lds[NBUF];

    const int n    = blockIdx.x;
    const int lane = threadIdx.x;       // 0..63, one wave
    const int col  = lane & 15;         // anchor: pixels 2col, 2col+1
    const int tg   = lane >> 4;
    const int dxl  = tg >> 1;
    const int sub  = tg & 1;

    for (int p = lane; p < NBUF; p += 64) lds[p] = 0u;
    __syncthreads();   // trivial (one wave); orders init vs image writes

    {   // image -> zx ch5..7 + h-plane indicator (ch6 = f16 1.0 interior)
        #pragma unroll 1
        for (int r = 0; r < 4; ++r) {
            int t = lane + r * 64;
            const int yy = t >> 3, xx0 = (t & 7) << 2;
            float4 i0 = *(const float4*)&image[(n * 3 + 0) * 1024 + yy * 32 + xx0];
            float4 i1 = *(const float4*)&image[(n * 3 + 1) * 1024 + yy * 32 + xx0];
            float4 i2 = *(const float4*)&image[(n * 3 + 2) * 1024 + yy * 32 + xx0];
            float a0[4] = {i0.x, i0.y, i0.z, i0.w};
            float a1[4] = {i1.x, i1.y, i1.z, i1.w};
            float a2[4] = {i2.x, i2.y, i2.z, i2.w};
            #pragma unroll
            for (int i = 0; i < 4; ++i) {
                unsigned* bp = (unsigned*)((char*)lds + bofs(yy + 2, xx0 + 2 + i));
                bp[2] = pk2(0.f, a0[i]);
                bp[3] = pk2(a1[i], a2[i]);
                unsigned* hp = (unsigned*)((char*)lds + bofs(yy + 2 + HOFF, xx0 + 2 + i));
                hp[3] = 0x00003C00u;     // pk2(1.0f16, 0)
            }
        }
    }

    // weight A-fragments: f1 + raw f2 in VGPRs (80 regs, iteration-invariant)
    uint4 f1[10], f2[10];
    #pragma unroll
    for (int c = 0; c < 10; ++c) {
        f1[c] = *(const uint4*)&wks[(c * 64 + lane) * 4];
        f2[c] = *(const uint4*)&wks[2560 + (c * 64 + lane) * 4];
    }

    int sx2[2];
    #pragma unroll
    for (int txh = 0; txh < 2; ++txh)
        sx2[txh] = swz(2 * col + 4 * txh + tg);

    const int chb = sub * 4;
    float b1q[4], b2q[4];
    #pragma unroll
    for (int r = 0; r < 4; ++r) {
        int oc = chb + r;
        b1q[r] = (oc < 6) ? b1[oc] : 0.f;
        b2q[r] = (oc < 5) ? b2[oc] : 0.f;
    }
    const f32x4 ai1 = {b1q[0], b1q[1], b1q[2], b1q[3]};
    const f32x4 ai2 = {b2q[0], b2q[1], b2q[2], b2q[3]};
    float gv[6], bv[6];
    #pragma unroll
    for (int c = 0; c < 6; ++c) { gv[c] = gam[c]; bv[c] = bet[c]; }

    __syncthreads();   // trivial

    const int hwx = swz(2 * col + dxl + 2);     // x-part of h/z write address

    #pragma unroll 1
    for (int it = 0; it < 30; ++it) {
        // ========== conv1: 4 row-bands, unnorm h out, stats in regs ==========
        float ps_lo = 0.f, ps_hi = 0.f, pq_lo = 0.f, pq_hi = 0.f;
        #pragma unroll 1
        for (int b = 0; b < 4; ++b) {
            const int ay = b << 3;
            f32x4 acc[8];
            #pragma unroll
            for (int g = 0; g < 8; ++g) acc[g] = ai1;
            #pragma unroll
            for (int pr = 0; pr < 12; ++pr) {
                const char* rowp = (const char*)lds + (ay + pr) * 576;
                #pragma unroll
                for (int txh = 0; txh < 2; ++txh) {
                    half8 pv = *(const half8*)(rowp + sx2[txh]);
                    #pragma unroll
                    for (int ty = 0; ty < 5; ++ty) {
                        const int g = pr - ty;
                        if (g >= 0 && g < 8)
                            acc[g] = __builtin_amdgcn_mfma_f32_16x16x32_f16(
                                __builtin_bit_cast(half8, f1[ty * 2 + txh]), pv, acc[g], 0, 0, 0);
                    }
                }
            }
            #pragma unroll
            for (int g = 0; g < 8; ++g) {
                float h0 = lrelu(acc[g][0]), h1 = lrelu(acc[g][1]);
                float h2 = lrelu(acc[g][2]), h3 = lrelu(acc[g][3]);
                ps_lo += h0 + h1;  pq_lo = fmaf(h0, h0, fmaf(h1, h1, pq_lo));
                ps_hi += h2 + h3;  pq_hi = fmaf(h2, h2, fmaf(h3, h3, pq_hi));
                char* wp = (char*)lds + (ay + g + 2 + HOFF) * 576 + hwx;
                if (sub == 0) {          // ch0-3: dwords 0,1
                    *(uint2*)wp = make_uint2(pk2(h0, h1), pk2(h2, h3));
                } else {                 // ch4,5: dword 2 only (indicator kept)
                    *(unsigned*)(wp + 8) = pk2(h0, h1);
                }
            }
        }

        // ---- wave-reduce stats (anchors xor 1..8, dx halves xor 32) ----
        #pragma unroll
        for (int m = 1; m <= 8; m <<= 1) {
            ps_lo += __shfl_xor(ps_lo, m); ps_hi += __shfl_xor(ps_hi, m);
            pq_lo += __shfl_xor(pq_lo, m); pq_hi += __shfl_xor(pq_hi, m);
        }
        ps_lo += __shfl_xor(ps_lo, 32); ps_hi += __shfl_xor(ps_hi, 32);
        pq_lo += __shfl_xor(pq_lo, 32); pq_hi += __shfl_xor(pq_hi, 32);
        // broadcast the 3 group sums (lane0: g0,g1; lane16: g2)
        float sg[3], qg[3];
        sg[0] = __shfl(ps_lo, 0);  qg[0] = __shfl(pq_lo, 0);
        sg[1] = __shfl(ps_hi, 0);  qg[1] = __shfl(pq_hi, 0);
        sg[2] = __shfl(ps_lo, 16); qg[2] = __shfl(pq_lo, 16);

        // ---- GN fold (per-thread, all 6 channels) ----
        float scv[6], shv[6];
        #pragma unroll
        for (int g3 = 0; g3 < 3; ++g3) {
            float mean = sg[g3] * (1.f / 2048.f);
            float var  = qg[g3] * (1.f / 2048.f) - mean * mean;
            float inv  = rsqrtf(var + 1e-5f);
            #pragma unroll
            for (int k = 0; k < 2; ++k) {
                int c = 2 * g3 + k;
                scv[c] = inv * gv[c];
                shv[c] = bv[c] - mean * scv[c];
            }
        }
        unsigned sp0 = pk2(scv[0], scv[1]), sp1 = pk2(scv[2], scv[3]), sp2 = pk2(scv[4], scv[5]);

        // ---- build folded conv2 frags: w2*sc + indicator weight (padw) ----
        uint4 fw[10];
        #pragma unroll
        for (int c = 0; c < 10; ++c) {
            float2 a = up2(f2[c].x), bb = up2(f2[c].y), cc = up2(f2[c].z);
            float pw = fmaf(a.x, shv[0], fmaf(a.y, shv[1],
                       fmaf(bb.x, shv[2], fmaf(bb.y, shv[3],
                       fmaf(cc.x, shv[4], cc.y * shv[5])))));
            fw[c].x = hmul2(f2[c].x, sp0);
            fw[c].y = hmul2(f2[c].y, sp1);
            fw[c].z = hmul2(f2[c].z, sp2);
            fw[c].w = pk2(pw, 0.f);
        }

        // ========== conv2: 4 row-bands over h plane + z RMW ==========
        #pragma unroll 1
        for (int b = 0; b < 4; ++b) {
            const int ay = b << 3;
            f32x4 acc[8];
            #pragma unroll
            for (int g = 0; g < 8; ++g) acc[g] = ai2;
            #pragma unroll
            for (int pr = 0; pr < 12; ++pr) {
                const char* rowp = (const char*)lds + (HOFF + ay + pr) * 576;
                #pragma unroll
                for (int txh = 0; txh < 2; ++txh) {
                    half8 pv = *(const half8*)(rowp + sx2[txh]);
                    #pragma unroll
                    for (int ty = 0; ty < 5; ++ty) {
                        const int g = pr - ty;
                        if (g >= 0 && g < 8)
                            acc[g] = __builtin_amdgcn_mfma_f32_16x16x32_f16(
                                __builtin_bit_cast(half8, fw[ty * 2 + txh]), pv, acc[g], 0, 0, 0);
                    }
                }
            }
            #pragma unroll
            for (int g = 0; g < 8; ++g) {
                char* zp = (char*)lds + (ay + g + 2) * 576 + hwx;
                if (sub == 0) {          // z0..z3: b64 RMW
                    uint2 zo = *(uint2*)zp;
                    float2 za = up2(zo.x), zc = up2(zo.y);
                    float z0 = 0.5f * za.x + 0.5f * lrelu(acc[g][0]);
                    float z1 = 0.5f * za.y + 0.5f * lrelu(acc[g][1]);
                    float z2 = 0.5f * zc.x + 0.5f * lrelu(acc[g][2]);
                    float z3 = 0.5f * zc.y + 0.5f * lrelu(acc[g][3]);
                    *(uint2*)zp = make_uint2(pk2(z0, z1), pk2(z2, z3));
                } else {                 // z4: u16 RMW (img0 hi half untouched)
                    _Float16* pz = (_Float16*)(zp + 8);
                    float z4 = 0.5f * (float)pz[0] + 0.5f * lrelu(acc[g][0]);
                    pz[0] = (_Float16)z4;
                }
            }
        }
        // no barrier: single wave, LDS ordering is hardware-enforced
    }

    // ================= head: out[o] = <z, wh[o]> + bh[o] =================
    {
        float ho[10];
        #pragma unroll
        for (int o = 0; o < 10; ++o) ho[o] = 0.f;
        #pragma unroll 1
        for (int r = 0; r < 4; ++r) {
            int grp = lane + r * 64;            // 4-px group index
            const int yy = grp >> 3, xx0 = (grp & 7) << 2;
            float zf[5][4];
            #pragma unroll
            for (int i = 0; i < 4; ++i) {
                const unsigned* bp = (const unsigned*)((const char*)lds + bofs(yy + 2, xx0 + 2 + i));
                float2 f0 = up2(bp[0]), fb = up2(bp[1]), fc = up2(bp[2]);
                zf[0][i] = f0.x; zf[1][i] = f0.y; zf[2][i] = fb.x; zf[3][i] = fb.y; zf[4][i] = fc.x;
            }
            #pragma unroll
            for (int c = 0; c < 5; ++c) {
                #pragma unroll
                for (int o = 0; o < 10; ++o) {
                    float4 wv = *(const float4*)&wh[(o * 5 + c) * 1024 + yy * 32 + xx0];
                    ho[o] = fmaf(zf[c][0], wv.x, ho[o]);
                    ho[o] = fmaf(zf[c][1], wv.y, ho[o]);
                    ho[o] = fmaf(zf[c][2], wv.z, ho[o]);
                    ho[o] = fmaf(zf[c][3], wv.w, ho[o]);
                }
            }
        }
        #pragma unroll
        for (int m = 1; m < 64; m <<= 1) {
            #pragma unroll
            for (int o = 0; o < 10; ++o) ho[o] += __shfl_xor(ho[o], m);
        }
        if (lane < 10)
            out[n * 10 + lane] = ho[lane] + bh[lane];
    }
}

extern "C" void kernel_launch(void* const* d_in, const int* in_sizes, int n_in,
                              void* d_out, int out_size, void* d_ws, size_t ws_size,
                              hipStream_t stream) {
    const float* image = (const float*)d_in[0];
    const float* w1    = (const float*)d_in[1];
    const float* b1    = (const float*)d_in[2];
    const float* gam   = (const float*)d_in[3];
    const float* bet   = (const float*)d_in[4];
    const float* w2    = (const float*)d_in[5];
    const float* b2    = (const float*)d_in[6];
    const float* wh    = (const float*)d_in[7];
    const float* bh    = (const float*)d_in[8];
    float* out = (float*)d_out;
    unsigned* ws = (unsigned*)d_ws;

    pack_weights<<<5, 256, 0, stream>>>(w1, w2, ws);

    const int N = in_sizes[0] / (3 * 32 * 32);   // 1024 images
    deq_kernel<<<N, 64, 0, stream>>>(image, ws, b1, gam, bet, b2, wh, bh, out);
}

// Round 24
// 304.768 us; speedup vs baseline: 1.3150x; 1.3150x over previous
//
#include <hip/hip_runtime.h>
#include <hip/hip_fp16.h>

// DEQ classifier, 128-THREAD / 2-WAVE-PER-IMAGE, indicator-GN, 2 barriers.
// 1024 blocks x 128 threads; block owns one image; wave w owns output rows
// 16w..16w+15 (two 8-row bands, acc[8] each). Tests the dispatch-geometry
// hypothesis: 64-thr blocks co-schedule 4/CU (R23) while 256-thr pin at 2
// (R9-R19). If 128-thr also gets 4/CU -> 8 waves/CU with 2-wave barrier
// scope + 2 waves/SIMD latency hiding (strictly better than R19's 4-wave
// coupling at equal occupancy).
// LDS: ONE 71-row x 36-bundle buffer (8-ch f16 bundles, 16B) = 40896 B:
//   rows 0..35 zx plane (interior 2..33; z0..z4,img0..2)
//   rows 34..69 h plane (interior 36..67), rows 34/35 shared ZERO pad
//   row 70: bundles 0..2 = GUARD (zero, absorbs tx=6/7 overreads; R18),
//           bytes 48..112 = red[16] stats scratch, bytes 128.. head scratch.
// Conv MFMA 16x16x32 row-reuse (R15): chunk (ty,txh) A=weight frag; ONE
// B-read per pixel row feeds outputs g=pr-ty. D: col=lane&15, row=(lane>>4)*4+reg.
// GN via R22-VERIFIED indicator trick: h ch6 = f16 1.0 interior (set once;
// sub==1 h-writes touch only dword2), h written UNNORMALIZED pre-B1; after
// B1 (publishes h AND stats) fw = {w2*sc, padw=w2.sh} -> exact normalized
// conv2, exact zero pads, no pad-rewrite. 2 barriers/iter (B1, B2=z halo).
// Frags f1/f2 in VGPRs (80) + fw transient (40): ~180 VGPR, launch_bounds
// (128,1) -> cap 256; 180*2 <= 512 so 2 waves/SIMD remain legal (m69).
// Tripwire: FETCH_SIZE ~7 MB; spill shows as FETCH/WRITE blowup.

typedef _Float16 half8 __attribute__((ext_vector_type(8)));
typedef float f32x4 __attribute__((ext_vector_type(4)));

#define HOFF 34
#define NBUF (71 * 36 * 4)        // 10224 dwords = 40896 B
#define GRDB (70 * 36 * 16)       // byte offset of row 70

__device__ __forceinline__ unsigned pk2(float a, float b) {
    __half2 h = __float22half2_rn(make_float2(a, b));
    return *reinterpret_cast<unsigned*>(&h);
}
__device__ __forceinline__ float2 up2(unsigned u) {
    __half2 h = *reinterpret_cast<__half2*>(&u);
    return __half22float2(h);
}
__device__ __forceinline__ unsigned hmul2(unsigned a, unsigned b) {
    __half2 r = __hmul2(*reinterpret_cast<__half2*>(&a), *reinterpret_cast<__half2*>(&b));
    return *reinterpret_cast<unsigned*>(&r);
}
__device__ __forceinline__ float lrelu(float x) { return fmaxf(x, 0.01f * x); }
__device__ __forceinline__ int swz(int x) { return (x * 16) ^ ((x & 8) << 1); }
__device__ __forceinline__ int bofs(int r, int x) { return r * 576 + swz(x); }

// ---- prep: row-reuse A-fragments (R15/R22 layout) ----
// ws[0..2559]    : conv1 frags, chunk c=(ty*2+txh), lane l:
//   row=l&15 (dx=row>>3, oc=row&7), tg=l>>4, tx=4*txh+tg, kx=tx-dx
//   elem pair d = ch (2d,2d+1): w1[oc][ch][ty][kx], 0 if oc>=6 or kx OOB
// ws[2560..5119] : conv2 frags from w2 (0 if oc>=5, ch>=6)
__global__ void pack_weights(const float* __restrict__ w1,
                             const float* __restrict__ w2,
                             unsigned* __restrict__ ws)
{
    int t = blockIdx.x * 256 + threadIdx.x;
    if (t < 640) {
        int c = t >> 6, l = t & 63;
        int row = l & 15, tg = l >> 4;
        int dx = row >> 3, oc = row & 7;
        int ty = c >> 1, tx = 4 * (c & 1) + tg, kx = tx - dx;
        unsigned q[4];
        #pragma unroll
        for (int d = 0; d < 4; ++d) {
            float v0 = 0.f, v1 = 0.f;
            if (oc < 6 && kx >= 0 && kx < 5) {
                v0 = w1[(oc * 8 + 2 * d) * 25 + ty * 5 + kx];
                v1 = w1[(oc * 8 + 2 * d + 1) * 25 + ty * 5 + kx];
            }
            q[d] = pk2(v0, v1);
        }
        *(uint4*)&ws[t * 4] = make_uint4(q[0], q[1], q[2], q[3]);
    } else if (t < 1280) {
        int u = t - 640;
        int c = u >> 6, l = u & 63;
        int row = l & 15, tg = l >> 4;
        int dx = row >> 3, oc = row & 7;
        int ty = c >> 1, tx = 4 * (c & 1) + tg, kx = tx - dx;
        unsigned q[4];
        #pragma unroll
        for (int d = 0; d < 4; ++d) {
            float v0 = 0.f, v1 = 0.f;
            if (oc < 5 && kx >= 0 && kx < 5) {
                if (2 * d < 6)     v0 = w2[(oc * 6 + 2 * d) * 25 + ty * 5 + kx];
                if (2 * d + 1 < 6) v1 = w2[(oc * 6 + 2 * d + 1) * 25 + ty * 5 + kx];
            }
            q[d] = pk2(v0, v1);
        }
        *(uint4*)&ws[2560 + u * 4] = make_uint4(q[0], q[1], q[2], q[3]);
    }
}

__global__ __launch_bounds__(128, 1)
void deq_kernel(const float* __restrict__ image,
                const unsigned* __restrict__ wks,
                const float* __restrict__ b1,
                const float* __restrict__ gam, const float* __restrict__ bet,
                const float* __restrict__ b2,
                const float* __restrict__ wh, const float* __restrict__ bh,
                float* __restrict__ out)
{
    __shared__ __align__(16) unsigned lds[NBUF];

    const int n    = blockIdx.x;
    const int tid  = threadIdx.x;       // 0..127
    const int lane = tid & 63;
    const int wid  = tid >> 6;          // 0..1: wave owns output rows 16w..+15
    const int col  = lane & 15;
    const int tg   = lane >> 4;
    const int dxl  = tg >> 1;
    const int sub  = tg & 1;

    float* const redf = (float*)((char*)lds + GRDB + 48);    // 16 floats
    float* const hsf  = (float*)((char*)lds + GRDB + 128);   // head scratch

    for (int p = tid; p < NBUF; p += 128) lds[p] = 0u;
    __syncthreads();

    {   // image -> zx ch5..7 + h-plane indicator (ch6 = f16 1.0 interior)
        #pragma unroll 1
        for (int r = 0; r < 2; ++r) {
            int t = tid + r * 128;
            const int yy = t >> 3, xx0 = (t & 7) << 2;
            float4 i0 = *(const float4*)&image[(n * 3 + 0) * 1024 + yy * 32 + xx0];
            float4 i1 = *(const float4*)&image[(n * 3 + 1) * 1024 + yy * 32 + xx0];
            float4 i2 = *(const float4*)&image[(n * 3 + 2) * 1024 + yy * 32 + xx0];
            float a0[4] = {i0.x, i0.y, i0.z, i0.w};
            float a1[4] = {i1.x, i1.y, i1.z, i1.w};
            float a2[4] = {i2.x, i2.y, i2.z, i2.w};
            #pragma unroll
            for (int i = 0; i < 4; ++i) {
                unsigned* bp = (unsigned*)((char*)lds + bofs(yy + 2, xx0 + 2 + i));
                bp[2] = pk2(0.f, a0[i]);
                bp[3] = pk2(a1[i], a2[i]);
                unsigned* hp = (unsigned*)((char*)lds + bofs(yy + 2 + HOFF, xx0 + 2 + i));
                hp[3] = 0x00003C00u;     // pk2(1.0f16, 0)
            }
        }
    }

    // weight A-fragments in VGPRs (80 regs, iteration-invariant)
    uint4 f1[10], f2[10];
    #pragma unroll
    for (int c = 0; c < 10; ++c) {
        f1[c] = *(const uint4*)&wks[(c * 64 + lane) * 4];
        f2[c] = *(const uint4*)&wks[2560 + (c * 64 + lane) * 4];
    }

    int sx2[2];
    #pragma unroll
    for (int txh = 0; txh < 2; ++txh)
        sx2[txh] = swz(2 * col + 4 * txh + tg);

    const int chb = sub * 4;
    float b1q[4], b2q[4];
    #pragma unroll
    for (int r = 0; r < 4; ++r) {
        int oc = chb + r;
        b1q[r] = (oc < 6) ? b1[oc] : 0.f;
        b2q[r] = (oc < 5) ? b2[oc] : 0.f;
    }
    const f32x4 ai1 = {b1q[0], b1q[1], b1q[2], b1q[3]};
    const f32x4 ai2 = {b2q[0], b2q[1], b2q[2], b2q[3]};
    float gv[6], bv[6];
    #pragma unroll
    for (int c = 0; c < 6; ++c) { gv[c] = gam[c]; bv[c] = bet[c]; }

    __syncthreads();

    const int hwx = swz(2 * col + dxl + 2);     // x-part of h/z write address
    const int wy0 = wid << 4;                   // wave's first output row

    #pragma unroll 1
    for (int it = 0; it < 30; ++it) {
        // ========== conv1: 2 bands of 8, unnorm h out, stats in regs ==========
        float ps_lo = 0.f, ps_hi = 0.f, pq_lo = 0.f, pq_hi = 0.f;
        #pragma unroll 1
        for (int b = 0; b < 2; ++b) {
            const int ay = wy0 + (b << 3);
            f32x4 acc[8];
            #pragma unroll
            for (int g = 0; g < 8; ++g) acc[g] = ai1;
            #pragma unroll
            for (int pr = 0; pr < 12; ++pr) {
                const char* rowp = (const char*)lds + (ay + pr) * 576;
                #pragma unroll
                for (int txh = 0; txh < 2; ++txh) {
                    half8 pv = *(const half8*)(rowp + sx2[txh]);
                    #pragma unroll
                    for (int ty = 0; ty < 5; ++ty) {
                        const int g = pr - ty;
                        if (g >= 0 && g < 8)
                            acc[g] = __builtin_amdgcn_mfma_f32_16x16x32_f16(
                                __builtin_bit_cast(half8, f1[ty * 2 + txh]), pv, acc[g], 0, 0, 0);
                    }
                }
            }
            #pragma unroll
            for (int g = 0; g < 8; ++g) {
                float h0 = lrelu(acc[g][0]), h1 = lrelu(acc[g][1]);
                float h2 = lrelu(acc[g][2]), h3 = lrelu(acc[g][3]);
                ps_lo += h0 + h1;  pq_lo = fmaf(h0, h0, fmaf(h1, h1, pq_lo));
                ps_hi += h2 + h3;  pq_hi = fmaf(h2, h2, fmaf(h3, h3, pq_hi));
                char* wp = (char*)lds + (ay + g + 2 + HOFF) * 576 + hwx;
                if (sub == 0) {          // ch0-3: dwords 0,1
                    *(uint2*)wp = make_uint2(pk2(h0, h1), pk2(h2, h3));
                } else {                 // ch4,5: dword 2 only (indicator kept)
                    *(unsigned*)(wp + 8) = pk2(h0, h1);
                }
            }
        }

        // ---- wave-reduce stats; cross-wave combine via red ----
        #pragma unroll
        for (int m = 1; m <= 8; m <<= 1) {
            ps_lo += __shfl_xor(ps_lo, m); ps_hi += __shfl_xor(ps_hi, m);
            pq_lo += __shfl_xor(pq_lo, m); pq_hi += __shfl_xor(pq_hi, m);
        }
        ps_lo += __shfl_xor(ps_lo, 32); ps_hi += __shfl_xor(ps_hi, 32);
        pq_lo += __shfl_xor(pq_lo, 32); pq_hi += __shfl_xor(pq_hi, 32);
        if (lane == 0)  { redf[wid * 8 + 0] = ps_lo; redf[wid * 8 + 1] = ps_hi;
                          redf[wid * 8 + 4] = pq_lo; redf[wid * 8 + 5] = pq_hi; }
        if (lane == 16) { redf[wid * 8 + 2] = ps_lo; redf[wid * 8 + 6] = pq_lo; }
        __syncthreads();                               // B1: h AND stats visible

        // ---- GN fold (all threads) ----
        float scv[6], shv[6];
        #pragma unroll
        for (int g3 = 0; g3 < 3; ++g3) {
            float s = redf[g3] + redf[8 + g3];
            float q = redf[4 + g3] + redf[12 + g3];
            float mean = s * (1.f / 2048.f);
            float var  = q * (1.f / 2048.f) - mean * mean;
            float inv  = rsqrtf(var + 1e-5f);
            #pragma unroll
            for (int k = 0; k < 2; ++k) {
                int c = 2 * g3 + k;
                scv[c] = inv * gv[c];
                shv[c] = bv[c] - mean * scv[c];
            }
        }
        unsigned sp0 = pk2(scv[0], scv[1]), sp1 = pk2(scv[2], scv[3]), sp2 = pk2(scv[4], scv[5]);

        // ---- folded conv2 frags: w2*sc + indicator weight (padw) ----
        uint4 fw[10];
        #pragma unroll
        for (int c = 0; c < 10; ++c) {
            float2 a = up2(f2[c].x), bb = up2(f2[c].y), cc = up2(f2[c].z);
            float pw = fmaf(a.x, shv[0], fmaf(a.y, shv[1],
                       fmaf(bb.x, shv[2], fmaf(bb.y, shv[3],
                       fmaf(cc.x, shv[4], cc.y * shv[5])))));
            fw[c].x = hmul2(f2[c].x, sp0);
            fw[c].y = hmul2(f2[c].y, sp1);
            fw[c].z = hmul2(f2[c].z, sp2);
            fw[c].w = pk2(pw, 0.f);
        }

        // ========== conv2: 2 bands over h plane + z RMW ==========
        #pragma unroll 1
        for (int b = 0; b < 2; ++b) {
            const int ay = wy0 + (b << 3);
            f32x4 acc[8];
            #pragma unroll
            for (int g = 0; g < 8; ++g) acc[g] = ai2;
            #pragma unroll
            for (int pr = 0; pr < 12; ++pr) {
                const char* rowp = (const char*)lds + (HOFF + ay + pr) * 576;
                #pragma unroll
                for (int txh = 0; txh < 2; ++txh) {
                    half8 pv = *(const half8*)(rowp + sx2[txh]);
                    #pragma unroll
                    for (int ty = 0; ty < 5; ++ty) {
                        const int g = pr - ty;
                        if (g >= 0 && g < 8)
                            acc[g] = __builtin_amdgcn_mfma_f32_16x16x32_f16(
                                __builtin_bit_cast(half8, fw[ty * 2 + txh]), pv, acc[g], 0, 0, 0);
                    }
                }
            }
            #pragma unroll
            for (int g = 0; g < 8; ++g) {
                char* zp = (char*)lds + (ay + g + 2) * 576 + hwx;
                if (sub == 0) {          // z0..z3: b64 RMW
                    uint2 zo = *(uint2*)zp;
                    float2 za = up2(zo.x), zc = up2(zo.y);
                    float z0 = 0.5f * za.x + 0.5f * lrelu(acc[g][0]);
                    float z1 = 0.5f * za.y + 0.5f * lrelu(acc[g][1]);
                    float z2 = 0.5f * zc.x + 0.5f * lrelu(acc[g][2]);
                    float z3 = 0.5f * zc.y + 0.5f * lrelu(acc[g][3]);
                    *(uint2*)zp = make_uint2(pk2(z0, z1), pk2(z2, z3));
                } else {                 // z4: u16 RMW (img0 hi half untouched)
                    _Float16* pz = (_Float16*)(zp + 8);
                    float z4 = 0.5f * (float)pz[0] + 0.5f * lrelu(acc[g][0]);
                    pz[0] = (_Float16)z4;
                }
            }
        }
        __syncthreads();                               // B2: z halo for next iter
    }

    // ================= head: out[o] = <z, wh[o]> + bh[o] =================
    {
        float ho[10];
        #pragma unroll
        for (int o = 0; o < 10; ++o) ho[o] = 0.f;
        #pragma unroll 1
        for (int r = 0; r < 2; ++r) {
            int grp = tid + r * 128;            // strip index
            const int yy = grp >> 3, xx0 = (grp & 7) << 2;
            float zf[5][4];
            #pragma unroll
            for (int i = 0; i < 4; ++i) {
                const unsigned* bp = (const unsigned*)((const char*)lds + bofs(yy + 2, xx0 + 2 + i));
                float2 f0 = up2(bp[0]), fb = up2(bp[1]), fc = up2(bp[2]);
                zf[0][i] = f0.x; zf[1][i] = f0.y; zf[2][i] = fb.x; zf[3][i] = fb.y; zf[4][i] = fc.x;
            }
            #pragma unroll
            for (int c = 0; c < 5; ++c) {
                #pragma unroll
                for (int o = 0; o < 10; ++o) {
                    float4 wv = *(const float4*)&wh[(o * 5 + c) * 1024 + yy * 32 + xx0];
                    ho[o] = fmaf(zf[c][0], wv.x, ho[o]);
                    ho[o] = fmaf(zf[c][1], wv.y, ho[o]);
                    ho[o] = fmaf(zf[c][2], wv.z, ho[o]);
                    ho[o] = fmaf(zf[c][3], wv.w, ho[o]);
                }
            }
        }
        #pragma unroll
        for (int m = 1; m < 64; m <<= 1) {
            #pragma unroll
            for (int o = 0; o < 10; ++o) ho[o] += __shfl_xor(ho[o], m);
        }
        if (lane == 0) {
            #pragma unroll
            for (int o = 0; o < 10; ++o) hsf[wid * 10 + o] = ho[o];
        }
    }
    __syncthreads();
    if (tid < 10)
        out[n * 10 + tid] = hsf[tid] + hsf[10 + tid] + bh[tid];
}

extern "C" void kernel_launch(void* const* d_in, const int* in_sizes, int n_in,
                              void* d_out, int out_size, void* d_ws, size_t ws_size,
                              hipStream_t stream) {
    const float* image = (const float*)d_in[0];
    const float* w1    = (const float*)d_in[1];
    const float* b1    = (const float*)d_in[2];
    const float* gam   = (const float*)d_in[3];
    const float* bet   = (const float*)d_in[4];
    const float* w2    = (const float*)d_in[5];
    const float* b2    = (const float*)d_in[6];
    const float* wh    = (const float*)d_in[7];
    const float* bh    = (const float*)d_in[8];
    float* out = (float*)d_out;
    unsigned* ws = (unsigned*)d_ws;

    pack_weights<<<5, 256, 0, stream>>>(w1, w2, ws);

    const int N = in_sizes[0] / (3 * 32 * 32);   // 1024 images
    deq_kernel<<<N, 128, 0, stream>>>(image, ws, b1, gam, bet, b2, wh, bh, out);
}